// Round 1
// baseline (554.746 us; speedup 1.0000x reference)
//
#include <hip/hip_runtime.h>

// MultiHeadAttention: B=32,S=512,E=256,H=8 (full-width heads)
// Pipeline: [proj Q][proj K(*pm)][proj V^T] -> [flash attn causal] -> [out proj + bias]
// All matmuls: bf16 MFMA 16x16x32, fp32 accum. 1/sqrt(E)=1/16 folded into Q store (exact).
// Workspace: Qb | Kb | Vt | AO, each 33,554,432 bf16 (67.1 MB) = 268.4 MB total.

typedef unsigned short u16;
typedef __attribute__((ext_vector_type(4))) unsigned short u16x4;
typedef __attribute__((ext_vector_type(8))) unsigned short u16x8;
typedef __attribute__((ext_vector_type(8))) __bf16 bf16x8;
typedef __attribute__((ext_vector_type(4))) float f32x4;

#define DI __device__ __forceinline__

DI u16 f2bf(float f) {  // round-to-nearest-even fp32 -> bf16
  unsigned int u = __builtin_bit_cast(unsigned int, f);
  u += 0x7fffu + ((u >> 16) & 1u);
  return (u16)(u >> 16);
}

DI bf16x8 lds_frag(const u16* p) {
  return __builtin_bit_cast(bf16x8, *(const u16x8*)p);
}

// ---------------------------------------------------------------------------
// Generic both-K-contiguous tiled GEMM: C[m,n] = sum_k A[m,k]*B[n,k] (+epilogue)
// MODE 0: Q proj   A=q fp32[16384,256]  B=Wq[h] fp32[256,256]  C=Qb bf16, *1/16
// MODE 1: K proj   same, *pm[m] (zero padded keys)             C=Kb bf16
// MODE 2: V^T proj A=Wv[h] fp32[256,256] B=v[b] fp32[512,256]  C=Vt bf16 [d][s]
// MODE 3: out proj A=AO bf16[16384,2048] B=Wo fp32[256,2048]   C=f32 + bo[n]
// Tile 128x128, BK=32, 256 threads (4 waves, each 64x64 = 4x4 MFMA frags).
// ---------------------------------------------------------------------------
template<int MODE>
__global__ __launch_bounds__(256) void gemm_bt(const void* __restrict__ Ag,
                                               const void* __restrict__ Bg,
                                               void* __restrict__ Cg,
                                               const float* __restrict__ extra) {
  constexpr int Kd = (MODE == 3) ? 2048 : 256;
  constexpr int LD = 40;  // 32 + 8 pad shorts: 80B row stride (16B-aligned, 2-way banks)
  __shared__ __attribute__((aligned(16))) u16 As[128][LD];
  __shared__ __attribute__((aligned(16))) u16 Bs[128][LD];

  const int tid = threadIdx.x;
  const int w = tid >> 6, l = tid & 63, lg = l >> 4, lc = l & 15;
  const int mt = blockIdx.x, nt = blockIdx.y, z = blockIdx.z;
  const int gm0 = mt * 128, gn0 = nt * 128;

  const float* Af = nullptr;
  const u16*   Ab = nullptr;
  const float* Bf = nullptr;
  if constexpr (MODE == 0 || MODE == 1) {
    Af = (const float*)Ag;                         // q/k rows = (b,s)
    Bf = (const float*)Bg + (size_t)z * 256 * 256; // W[h]
  } else if constexpr (MODE == 2) {
    const int b = z >> 3, h = z & 7;
    Af = (const float*)Ag + (size_t)h * 256 * 256; // Wv[h] rows = d
    Bf = (const float*)Bg + (size_t)b * 512 * 256; // v[b]  rows = s
  } else {
    Ab = (const u16*)Ag;                           // AO bf16
    Bf = (const float*)Bg;                         // Wo
  }

  const f32x4 zero = {0.f, 0.f, 0.f, 0.f};
  f32x4 acc[4][4];
#pragma unroll
  for (int i = 0; i < 4; ++i)
#pragma unroll
    for (int j = 0; j < 4; ++j) acc[i][j] = zero;

  const int wm = (w & 1) * 64, wn = (w >> 1) * 64;

  for (int k0 = 0; k0 < Kd; k0 += 32) {
    __syncthreads();
    // --- stage A tile [128][32] ---
    if constexpr (MODE == 3) {
#pragma unroll
      for (int p = 0; p < 2; ++p) {
        const int c = p * 256 + tid;
        const int row = c >> 2, col = (c & 3) * 8;
        *(u16x8*)&As[row][col] =
            *(const u16x8*)(Ab + (size_t)(gm0 + row) * Kd + k0 + col);
      }
    } else {
#pragma unroll
      for (int p = 0; p < 4; ++p) {
        const int row = p * 32 + (tid >> 3), col = (tid & 7) * 4;
        f32x4 vv = *(const f32x4*)(Af + (size_t)(gm0 + row) * Kd + k0 + col);
        u16x4 o = {f2bf(vv.x), f2bf(vv.y), f2bf(vv.z), f2bf(vv.w)};
        *(u16x4*)&As[row][col] = o;
      }
    }
    // --- stage B tile [128][32] (always fp32 source) ---
#pragma unroll
    for (int p = 0; p < 4; ++p) {
      const int row = p * 32 + (tid >> 3), col = (tid & 7) * 4;
      f32x4 vv = *(const f32x4*)(Bf + (size_t)(gn0 + row) * Kd + k0 + col);
      u16x4 o = {f2bf(vv.x), f2bf(vv.y), f2bf(vv.z), f2bf(vv.w)};
      *(u16x4*)&Bs[row][col] = o;
    }
    __syncthreads();

    bf16x8 afr[4], bfr[4];
#pragma unroll
    for (int i = 0; i < 4; ++i) afr[i] = lds_frag(&As[wm + i * 16 + lc][lg * 8]);
#pragma unroll
    for (int j = 0; j < 4; ++j) bfr[j] = lds_frag(&Bs[wn + j * 16 + lc][lg * 8]);
#pragma unroll
    for (int i = 0; i < 4; ++i)
#pragma unroll
      for (int j = 0; j < 4; ++j)
        acc[i][j] = __builtin_amdgcn_mfma_f32_16x16x32_bf16(afr[i], bfr[j],
                                                            acc[i][j], 0, 0, 0);
  }

  // --- epilogue. C-frag: col = lc, row = lg*4 + ii (m89-verified layout) ---
#pragma unroll
  for (int i = 0; i < 4; ++i) {
#pragma unroll
    for (int j = 0; j < 4; ++j) {
#pragma unroll
      for (int ii = 0; ii < 4; ++ii) {
        const int m = gm0 + wm + i * 16 + lg * 4 + ii;
        const int n = gn0 + wn + j * 16 + lc;
        float v = acc[i][j][ii];
        if constexpr (MODE == 0 || MODE == 1) {
          if constexpr (MODE == 0) v *= 0.0625f;   // 1/sqrt(256), exact
          else                     v *= extra[m];  // padding mask, m = b*512+s
          const int b = m >> 9, s = m & 511;
          ((u16*)Cg)[((size_t)(b * 8 + z) * 512 + s) * 256 + n] = f2bf(v);
        } else if constexpr (MODE == 2) {
          ((u16*)Cg)[((size_t)z * 256 + m) * 512 + n] = f2bf(v);  // Vt[bh][d][s]
        } else {
          ((float*)Cg)[(size_t)m * 256 + n] = v + extra[n];       // + bo
        }
      }
    }
  }
}

// ---------------------------------------------------------------------------
// Flash attention, causal. Block = one (b,h) x one 64-row q-tile, 4 waves.
// Wave owns 16 q rows; Q frags live in registers (d=256 -> 8 bf16x8).
// Per k-tile (64 keys): stage K[64][256], Vt[256][64] in LDS; S=QK^T (MFMA);
// causal mask; online softmax (16-lane shfl row-reduce); P->bf16 via per-wave
// LDS round trip; PV MFMA into 16x f32x4 accum (16q x 256d).
// ---------------------------------------------------------------------------
__global__ __launch_bounds__(256) void attn_k(const u16* __restrict__ Qb,
                                              const u16* __restrict__ Kb,
                                              const u16* __restrict__ Vt,
                                              u16* __restrict__ AO) {
  __shared__ __attribute__((aligned(16))) u16 Ks[64][264];   // 64 keys x 256d (+8 pad)
  __shared__ __attribute__((aligned(16))) u16 Vs[256][72];   // 256 d x 64 s (+8 pad)
  __shared__ __attribute__((aligned(16))) u16 Ps[4][16][72]; // per-wave P 16q x 64k

  const int qt = blockIdx.x;   // q tile 0..7
  const int bh = blockIdx.y;   // 0..255
  const int b = bh >> 3, h = bh & 7;
  const int tid = threadIdx.x;
  const int w = tid >> 6, l = tid & 63, lg = l >> 4, lc = l & 15;

  const u16* Qbh = Qb + (size_t)bh * (512 * 256);
  const u16* Kbh = Kb + (size_t)bh * (512 * 256);
  const u16* Vbh = Vt + (size_t)bh * (256 * 512);

  // Q fragments (already scaled by 1/16): wave rows qt*64 + w*16 + lc
  bf16x8 qf[8];
  {
    const u16* qp = Qbh + (size_t)(qt * 64 + w * 16 + lc) * 256 + lg * 8;
#pragma unroll
    for (int kc = 0; kc < 8; ++kc)
      qf[kc] = __builtin_bit_cast(bf16x8, *(const u16x8*)(qp + kc * 32));
  }

  const f32x4 zero = {0.f, 0.f, 0.f, 0.f};
  f32x4 acc[16];
#pragma unroll
  for (int i = 0; i < 16; ++i) acc[i] = zero;
  float m_run[4], l_run[4];
#pragma unroll
  for (int i = 0; i < 4; ++i) { m_run[i] = -3.0e38f; l_run[i] = 0.f; }

  for (int kt = 0; kt <= qt; ++kt) {
    __syncthreads();  // protect K/V LDS from previous iteration readers
    // stage K tile: 8 passes, 32 lanes cover one 512B row
#pragma unroll
    for (int p = 0; p < 8; ++p) {
      const int row = p * 8 + (tid >> 5), col = (tid & 31) * 8;
      *(u16x8*)&Ks[row][col] =
          *(const u16x8*)(Kbh + (size_t)(kt * 64 + row) * 256 + col);
    }
    // stage Vt tile: 8 passes, 8 lanes cover one 128B row segment
#pragma unroll
    for (int p = 0; p < 8; ++p) {
      const int row = p * 32 + (tid >> 3), col = (tid & 7) * 8;
      *(u16x8*)&Vs[row][col] =
          *(const u16x8*)(Vbh + (size_t)row * 512 + kt * 64 + col);
    }
    __syncthreads();

    // S = Q K^T  (16q x 64k per wave)
    f32x4 sacc[4];
#pragma unroll
    for (int nf = 0; nf < 4; ++nf) sacc[nf] = zero;
#pragma unroll
    for (int nf = 0; nf < 4; ++nf)
#pragma unroll
      for (int kc = 0; kc < 8; ++kc) {
        bf16x8 kf = lds_frag(&Ks[nf * 16 + lc][kc * 32 + lg * 8]);
        sacc[nf] = __builtin_amdgcn_mfma_f32_16x16x32_bf16(qf[kc], kf, sacc[nf], 0, 0, 0);
      }

    // causal mask + tile row-max
    const int qrow0 = qt * 64 + w * 16 + lg * 4;  // + ii
    const int kcol0 = kt * 64 + lc;               // + nf*16
    float mt[4] = {-3.0e38f, -3.0e38f, -3.0e38f, -3.0e38f};
#pragma unroll
    for (int nf = 0; nf < 4; ++nf)
#pragma unroll
      for (int i = 0; i < 4; ++i) {
        float s = sacc[nf][i];
        if (kcol0 + nf * 16 > qrow0 + i) s = -3.0e38f;
        sacc[nf][i] = s;
        mt[i] = fmaxf(mt[i], s);
      }
#pragma unroll
    for (int i = 0; i < 4; ++i)
#pragma unroll
      for (int off = 1; off < 16; off <<= 1)
        mt[i] = fmaxf(mt[i], __shfl_xor(mt[i], off));

    float sf[4], rs[4];
#pragma unroll
    for (int i = 0; i < 4; ++i) {
      const float mn = fmaxf(m_run[i], mt[i]);
      sf[i] = __expf(m_run[i] - mn);  // first iter: exp(-inf) = 0
      m_run[i] = mn;
      rs[i] = 0.f;
    }

    // P = exp(S - m), write bf16 P to per-wave LDS region
#pragma unroll
    for (int nf = 0; nf < 4; ++nf)
#pragma unroll
      for (int i = 0; i < 4; ++i) {
        const float p = __expf(sacc[nf][i] - m_run[i]);
        rs[i] += p;
        Ps[w][lg * 4 + i][nf * 16 + lc] = f2bf(p);
      }
#pragma unroll
    for (int i = 0; i < 4; ++i) {
      float r = rs[i];
#pragma unroll
      for (int off = 1; off < 16; off <<= 1) r += __shfl_xor(r, off);
      l_run[i] = l_run[i] * sf[i] + r;
    }
    // rescale O accumulator
#pragma unroll
    for (int nf = 0; nf < 16; ++nf)
#pragma unroll
      for (int i = 0; i < 4; ++i) acc[nf][i] *= sf[i];

    __syncthreads();  // safety: P cross-lane LDS round trip ordering

    // PV: A = P[16q x 64k], B = Vt[256d x 64k] -> acc[16q x 256d]
    bf16x8 pf[2];
#pragma unroll
    for (int kc = 0; kc < 2; ++kc)
      pf[kc] = lds_frag(&Ps[w][lc][kc * 32 + lg * 8]);
#pragma unroll
    for (int nf = 0; nf < 16; ++nf)
#pragma unroll
      for (int kc = 0; kc < 2; ++kc) {
        bf16x8 vf = lds_frag(&Vs[nf * 16 + lc][kc * 32 + lg * 8]);
        acc[nf] = __builtin_amdgcn_mfma_f32_16x16x32_bf16(pf[kc], vf, acc[nf], 0, 0, 0);
      }
  }

  // epilogue: AO[b, s=q, h, d] = acc / l
#pragma unroll
  for (int i = 0; i < 4; ++i) {
    const float inv = 1.0f / l_run[i];
    const int q = qt * 64 + w * 16 + lg * 4 + i;
    u16* op = AO + ((size_t)(b * 512 + q) * 8 + h) * 256;
#pragma unroll
    for (int nf = 0; nf < 16; ++nf) op[nf * 16 + lc] = f2bf(acc[nf][i] * inv);
  }
}

// ---------------------------------------------------------------------------
extern "C" void kernel_launch(void* const* d_in, const int* in_sizes, int n_in,
                              void* d_out, int out_size, void* d_ws, size_t ws_size,
                              hipStream_t stream) {
  const float* q  = (const float*)d_in[0];
  const float* k  = (const float*)d_in[1];
  const float* v  = (const float*)d_in[2];
  const float* pm = (const float*)d_in[3];
  // d_in[4] = attn_mask: deterministic causal, applied analytically
  const float* Wq = (const float*)d_in[5];
  const float* Wk = (const float*)d_in[6];
  const float* Wv = (const float*)d_in[7];
  const float* Wo = (const float*)d_in[8];
  const float* bo = (const float*)d_in[9];

  const size_t NBH = 33554432ull;  // B*H*S*E
  u16* Qb = (u16*)d_ws;
  u16* Kf = Qb + NBH;
  u16* Vt = Kf + NBH;
  u16* AO = Vt + NBH;

  const dim3 blk(256, 1, 1);
  gemm_bt<0><<<dim3(128, 2, 8),   blk, 0, stream>>>(q,  Wq, Qb, nullptr);
  gemm_bt<1><<<dim3(128, 2, 8),   blk, 0, stream>>>(k,  Wk, Kf, pm);
  gemm_bt<2><<<dim3(2, 4, 256),   blk, 0, stream>>>(Wv, v,  Vt, nullptr);
  attn_k    <<<dim3(8, 256, 1),   blk, 0, stream>>>(Qb, Kf, Vt, AO);
  gemm_bt<3><<<dim3(128, 2, 1),   blk, 0, stream>>>(AO, Wo, d_out, bo);
}

// Round 2
// 441.297 us; speedup vs baseline: 1.2571x; 1.2571x over previous
//
#include <hip/hip_runtime.h>

// MultiHeadAttention: B=32,S=512,E=256,H=8 (full-width heads)
// [proj Q][proj K(*pm)][proj V^T] -> [flash attn causal, swapped-QK] -> [out proj + bias]
// bf16 MFMA 16x16x32, fp32 accum. 1/sqrt(E)=1/16 folded into Q store.
// Workspace: Qb | Kb | Vt | AO, each 33,554,432 bf16 = 268.4 MB total.

typedef unsigned short u16;
typedef __attribute__((ext_vector_type(4))) unsigned short u16x4;
typedef __attribute__((ext_vector_type(8))) unsigned short u16x8;
typedef __attribute__((ext_vector_type(8))) __bf16 bf16x8;
typedef __attribute__((ext_vector_type(4))) float f32x4;
typedef __attribute__((ext_vector_type(2))) unsigned int u32x2;

#define DI __device__ __forceinline__

DI u16 cvt(float f) { return __builtin_bit_cast(u16, (__bf16)f); }  // HW RNE cvt

DI void gl_lds16(const void* g, void* l) {  // 16B global->LDS direct (per-lane gsrc, wave-uniform LDS base)
  __builtin_amdgcn_global_load_lds((const __attribute__((address_space(1))) unsigned int*)g,
                                   (__attribute__((address_space(3))) unsigned int*)l, 16, 0, 0);
}

DI bf16x8 lds16(const void* base, int byte_off) {
  return __builtin_bit_cast(bf16x8, *(const u16x8*)((const char*)base + byte_off));
}

// ---------------------------------------------------------------------------
// Tiled both-K-contiguous GEMM: C[m,n] = sum_k A[m,k]*B[n,k] (+epilogue)
// MODE 0: Q proj  A=q f32[16384,256]  B=Wq[h] f32  -> Qb bf16, *1/16
// MODE 1: K proj  same with Wk, *pm[m]             -> Kb bf16
// MODE 2: V^T     A=Wv[h] f32[256,256] B=v[b] f32  -> Vt bf16 [bh][d][s]
// MODE 3: out     A=AO bf16[16384,2048] B=Wo f32   -> f32 + bo[n]
// 128x128 tile, BK=64, 256 thr (4 waves x 64x64). XOR-swizzled LDS (16B slots).
// ---------------------------------------------------------------------------
template<int MODE>
__global__ __launch_bounds__(256) void gemm_bt(const void* __restrict__ Ag,
                                               const void* __restrict__ Bg,
                                               void* __restrict__ Cg,
                                               const float* __restrict__ extra) {
  constexpr int Kd = (MODE == 3) ? 2048 : 256;
  __shared__ __attribute__((aligned(16))) u16 As[128 * 64];
  __shared__ __attribute__((aligned(16))) u16 Bs[128 * 64];

  const int tid = threadIdx.x;
  const int w = tid >> 6, l = tid & 63, lg = l >> 4, lc = l & 15;
  const int gm0 = blockIdx.x * 128, gn0 = blockIdx.y * 128;
  const int z = blockIdx.z;

  const float* Af = nullptr;
  const u16*   Ab = nullptr;
  const float* Bf = nullptr;
  if constexpr (MODE == 0 || MODE == 1) {
    Af = (const float*)Ag;
    Bf = (const float*)Bg + (size_t)z * 256 * 256;
  } else if constexpr (MODE == 2) {
    Af = (const float*)Ag + (size_t)(z & 7) * 256 * 256;   // Wv[h]
    Bf = (const float*)Bg + (size_t)(z >> 3) * 512 * 256;  // v[b]
  } else {
    Ab = (const u16*)Ag;
    Bf = (const float*)Bg;
  }

  const f32x4 zero = {0.f, 0.f, 0.f, 0.f};
  f32x4 acc[4][4];
#pragma unroll
  for (int i = 0; i < 4; ++i)
#pragma unroll
    for (int j = 0; j < 4; ++j) acc[i][j] = zero;

  const int wm = (w & 1) * 64, wn = (w >> 1) * 64;

  for (int k0 = 0; k0 < Kd; k0 += 64) {
    __syncthreads();
    // ---- stage A [128][64] bf16 ----
    if constexpr (MODE == 3) {
#pragma unroll
      for (int p = 0; p < 4; ++p) {
        const int r0 = (w * 4 + p) * 8;
        const int row = r0 + (l >> 3);
        const u16* g = Ab + (size_t)(gm0 + row) * Kd + k0 + (((l & 7) << 3) ^ ((row & 7) << 3));
        gl_lds16(g, &As[r0 * 64]);
      }
    } else {
#pragma unroll
      for (int p = 0; p < 8; ++p) {
        const int row = p * 16 + (tid >> 4), c4 = (tid & 15) * 4;
        f32x4 v = *(const f32x4*)(Af + (size_t)(gm0 + row) * Kd + k0 + c4);
        u16x4 o = {cvt(v.x), cvt(v.y), cvt(v.z), cvt(v.w)};
        *(u16x4*)((char*)As + row * 128 + ((c4 * 2) ^ ((row & 7) << 4))) = o;
      }
    }
    // ---- stage B [128][64] bf16 (fp32 src) ----
#pragma unroll
    for (int p = 0; p < 8; ++p) {
      const int row = p * 16 + (tid >> 4), c4 = (tid & 15) * 4;
      f32x4 v = *(const f32x4*)(Bf + (size_t)(gn0 + row) * Kd + k0 + c4);
      u16x4 o = {cvt(v.x), cvt(v.y), cvt(v.z), cvt(v.w)};
      *(u16x4*)((char*)Bs + row * 128 + ((c4 * 2) ^ ((row & 7) << 4))) = o;
    }
    __syncthreads();

#pragma unroll
    for (int kc = 0; kc < 2; ++kc) {
      bf16x8 afr[4], bfr[4];
#pragma unroll
      for (int i = 0; i < 4; ++i)
        afr[i] = lds16(As, (wm + 16 * i + lc) * 128 + ((kc * 64 + lg * 16) ^ ((lc & 7) << 4)));
#pragma unroll
      for (int j = 0; j < 4; ++j)
        bfr[j] = lds16(Bs, (wn + 16 * j + lc) * 128 + ((kc * 64 + lg * 16) ^ ((lc & 7) << 4)));
#pragma unroll
      for (int i = 0; i < 4; ++i)
#pragma unroll
        for (int j = 0; j < 4; ++j)
          acc[i][j] = __builtin_amdgcn_mfma_f32_16x16x32_bf16(afr[i], bfr[j], acc[i][j], 0, 0, 0);
    }
  }

  // ---- epilogue. C-frag: col=lc, row=lg*4+ii ----
#pragma unroll
  for (int i = 0; i < 4; ++i) {
#pragma unroll
    for (int j = 0; j < 4; ++j) {
#pragma unroll
      for (int ii = 0; ii < 4; ++ii) {
        const int m = gm0 + wm + i * 16 + lg * 4 + ii;
        const int n = gn0 + wn + j * 16 + lc;
        float v = acc[i][j][ii];
        if constexpr (MODE == 0 || MODE == 1) {
          if constexpr (MODE == 0) v *= 0.0625f;
          else                     v *= extra[m];  // padding mask
          const int b = m >> 9, s = m & 511;
          ((u16*)Cg)[((size_t)(b * 8 + z) * 512 + s) * 256 + n] = cvt(v);
        } else if constexpr (MODE == 2) {
          ((u16*)Cg)[((size_t)z * 256 + m) * 512 + n] = cvt(v);  // Vt[bh][d][s]
        } else {
          ((float*)Cg)[(size_t)m * 256 + n] = v + extra[n];
        }
      }
    }
  }
}

// ---------------------------------------------------------------------------
// Flash attention, causal, swapped-QK. Block = (qt: 128 q rows) x (bh), 8 waves.
// Wave w owns q rows qt*128+w*16..+15; Q in regs. Per 64-key tile:
//   stage K[64][256], Vt[256][64] via global_load_lds (XOR-swizzled source);
//   S^T = mfma(K,Q): lane holds S[key=16nf+4lg+i][q=lc] -> per-lane softmax
//   (15 in-lane + 2 shfl_xor); P transposed via per-wave swizzled LDS; PV MFMA.
// LDS: 32+32+16 = 80 KB. 2 barriers/iter.
// ---------------------------------------------------------------------------
__global__ __launch_bounds__(512) void attn_k(const u16* __restrict__ Qb,
                                              const u16* __restrict__ Kb,
                                              const u16* __restrict__ Vt,
                                              u16* __restrict__ AO) {
  __shared__ __attribute__((aligned(16))) u16 Ks[64 * 256];   // [key][d], swizzled
  __shared__ __attribute__((aligned(16))) u16 Vs[256 * 64];   // [d][key], swizzled
  __shared__ __attribute__((aligned(16))) u16 Ps[8][16 * 64]; // per-wave [q][key], swizzled

  const int qt = blockIdx.x, bh = blockIdx.y;
  const int b = bh >> 3, h = bh & 7;
  const int tid = threadIdx.x;
  const int w = tid >> 6, l = tid & 63, lg = l >> 4, lc = l & 15;

  const u16* Qbh = Qb + (size_t)bh * (512 * 256);
  const u16* Kbh = Kb + (size_t)bh * (512 * 256);
  const u16* Vbh = Vt + (size_t)bh * (256 * 512);

  // Q frags (scaled already): B-operand layout = Q[q=lc][d=lg*8+j+32kc]
  bf16x8 qf[8];
  {
    const u16* qp = Qbh + (size_t)(qt * 128 + w * 16 + lc) * 256 + lg * 8;
#pragma unroll
    for (int kc = 0; kc < 8; ++kc)
      qf[kc] = __builtin_bit_cast(bf16x8, *(const u16x8*)(qp + kc * 32));
  }

  const f32x4 zero = {0.f, 0.f, 0.f, 0.f};
  f32x4 acc[16];  // O[q=lg*4+i][d=16nfd+lc]
#pragma unroll
  for (int i = 0; i < 16; ++i) acc[i] = zero;
  float m_run = -3.0e38f, l_run = 0.f;  // per-lane, q = qt*128+w*16+lc

  const int qrow = qt * 128 + w * 16 + lc;
  const int qmaxw = qt * 128 + w * 16 + 15;
  const int nkt = 2 * qt + 2;

  for (int kt = 0; kt < nkt; ++kt) {
    __syncthreads();  // prev-tile readers done
    // ---- stage K: 32 x 1KB instr (4/wave); source pre-swizzled ----
#pragma unroll
    for (int p = 0; p < 4; ++p) {
      const int r0 = w * 8 + p * 2;
      const int row = r0 + (l >> 5);
      const u16* g = Kbh + (size_t)(kt * 64 + row) * 256 + (((l & 31) << 3) ^ ((row & 7) << 3));
      gl_lds16(g, &Ks[r0 * 256]);
    }
    // ---- stage V: 32 x 1KB instr (4/wave) ----
#pragma unroll
    for (int p = 0; p < 4; ++p) {
      const int r0 = w * 32 + p * 8;
      const int row = r0 + (l >> 3);
      const u16* g = Vbh + (size_t)row * 512 + kt * 64 + (((l & 7) << 3) ^ ((row & 7) << 3));
      gl_lds16(g, &Vs[r0 * 64]);
    }
    __syncthreads();  // drains vmcnt -> LDS ready

    if (kt * 64 <= qmaxw) {  // wave-uniform causal skip
      // ---- S^T = mfma(K, Q): st[nf][i] = S[key=64kt+16nf+4lg+i][q=lc] ----
      f32x4 st[4];
#pragma unroll
      for (int nf = 0; nf < 4; ++nf) st[nf] = zero;
#pragma unroll
      for (int nf = 0; nf < 4; ++nf) {
        const int row = nf * 16 + lc;
#pragma unroll
        for (int kc = 0; kc < 8; ++kc) {
          bf16x8 kf = lds16(Ks, row * 512 + ((kc * 64 + lg * 16) ^ ((lc & 7) << 4)));
          st[nf] = __builtin_amdgcn_mfma_f32_16x16x32_bf16(kf, qf[kc], st[nf], 0, 0, 0);
        }
      }
      // ---- causal mask + row max (per-lane over 16, then 2 shfl) ----
      float mt = -3.0e38f;
#pragma unroll
      for (int nf = 0; nf < 4; ++nf)
#pragma unroll
        for (int i = 0; i < 4; ++i) {
          const int key = kt * 64 + nf * 16 + lg * 4 + i;
          float s = st[nf][i];
          if (key > qrow) s = -3.0e38f;
          st[nf][i] = s;
          mt = fmaxf(mt, s);
        }
      mt = fmaxf(mt, __shfl_xor(mt, 16));
      mt = fmaxf(mt, __shfl_xor(mt, 32));
      const float mn = fmaxf(m_run, mt);
      const float sf = __expf(m_run - mn);
      m_run = mn;

      float rs = 0.f;
      unsigned int pw[8];
#pragma unroll
      for (int nf = 0; nf < 4; ++nf)
#pragma unroll
        for (int c = 0; c < 2; ++c) {
          const float p0 = __expf(st[nf][2 * c] - mn);
          const float p1 = __expf(st[nf][2 * c + 1] - mn);
          rs += p0 + p1;
          pw[nf * 2 + c] = (unsigned int)cvt(p0) | ((unsigned int)cvt(p1) << 16);
        }
      rs += __shfl_xor(rs, 16);
      rs += __shfl_xor(rs, 32);
      l_run = l_run * sf + rs;

      float sfi[4];
#pragma unroll
      for (int i = 0; i < 4; ++i) sfi[i] = __shfl(sf, lg * 4 + i);
#pragma unroll
      for (int nfd = 0; nfd < 16; ++nfd)
#pragma unroll
        for (int i = 0; i < 4; ++i) acc[nfd][i] *= sfi[i];

      // ---- P transpose through per-wave swizzled LDS (wave-private) ----
      char* pb = (char*)&Ps[w][0];
#pragma unroll
      for (int nf = 0; nf < 4; ++nf) {
        u32x2 pr = {pw[nf * 2], pw[nf * 2 + 1]};
        *(u32x2*)(pb + (lc * 128 + ((nf * 32 + lg * 8) ^ ((lc & 7) << 4)))) = pr;
      }
      bf16x8 pf[2];
#pragma unroll
      for (int kc = 0; kc < 2; ++kc)
        pf[kc] = lds16(pb, lc * 128 + ((kc * 64 + lg * 16) ^ ((lc & 7) << 4)));

      // ---- PV: acc[nfd] += P[q][k] * Vt[d][k] ----
#pragma unroll
      for (int nfd = 0; nfd < 16; ++nfd) {
        const int row = nfd * 16 + lc;
#pragma unroll
        for (int kc = 0; kc < 2; ++kc) {
          bf16x8 vf = lds16(Vs, row * 128 + ((kc * 64 + lg * 16) ^ ((lc & 7) << 4)));
          acc[nfd] = __builtin_amdgcn_mfma_f32_16x16x32_bf16(pf[kc], vf, acc[nfd], 0, 0, 0);
        }
      }
    }
  }

  // ---- epilogue: AO[b, q, h, d] = acc / l ----
  const float inv = 1.0f / l_run;
#pragma unroll
  for (int i = 0; i < 4; ++i) {
    const float li = __shfl(inv, lg * 4 + i);
    const int q = qt * 128 + w * 16 + lg * 4 + i;
    u16* op = AO + ((size_t)(b * 512 + q) * 8 + h) * 256 + lc;
#pragma unroll
    for (int nfd = 0; nfd < 16; ++nfd) op[nfd * 16] = cvt(acc[nfd][i] * li);
  }
}

// ---------------------------------------------------------------------------
extern "C" void kernel_launch(void* const* d_in, const int* in_sizes, int n_in,
                              void* d_out, int out_size, void* d_ws, size_t ws_size,
                              hipStream_t stream) {
  const float* q  = (const float*)d_in[0];
  const float* k  = (const float*)d_in[1];
  const float* v  = (const float*)d_in[2];
  const float* pm = (const float*)d_in[3];
  // d_in[4] = attn_mask: deterministic causal, applied analytically
  const float* Wq = (const float*)d_in[5];
  const float* Wk = (const float*)d_in[6];
  const float* Wv = (const float*)d_in[7];
  const float* Wo = (const float*)d_in[8];
  const float* bo = (const float*)d_in[9];

  const size_t NBH = 33554432ull;  // B*H*S*E
  u16* Qb = (u16*)d_ws;
  u16* Kf = Qb + NBH;
  u16* Vt = Kf + NBH;
  u16* AO = Vt + NBH;

  gemm_bt<0><<<dim3(128, 2, 8), 256, 0, stream>>>(q,  Wq, Qb, nullptr);
  gemm_bt<1><<<dim3(128, 2, 8), 256, 0, stream>>>(k,  Wk, Kf, pm);
  gemm_bt<2><<<dim3(2, 4, 256), 256, 0, stream>>>(Wv, v,  Vt, nullptr);
  attn_k    <<<dim3(4, 256, 1), 512, 0, stream>>>(Qb, Kf, Vt, AO);
  gemm_bt<3><<<dim3(128, 2, 1), 256, 0, stream>>>(AO, Wo, d_out, bo);
}